// Round 1
// baseline (5747.936 us; speedup 1.0000x reference)
//
#include <hip/hip_runtime.h>
#include <math.h>

#define HW 16384      // 128*128
#define BATCH 4
#define KIDS 20

// ---------------- direct 3x3 conv, SAME padding, NCHW ----------------
// block = 256 threads -> 16x16 spatial tile; each thread computes COB=8
// output channels at one pixel. Per ci: 9 (L1-cached) input loads + 72 FMA.
template<int Ci, int COB>
__global__ __launch_bounds__(256) void conv3x3_k(
    const float* __restrict__ in, const float* __restrict__ wt,
    const float* __restrict__ bias, float* __restrict__ out, int Co)
{
  const int tx = threadIdx.x & 15, ty = threadIdx.x >> 4;
  const int x = blockIdx.x * 16 + tx;
  const int y = blockIdx.y * 16 + ty;
  const int coChunks = Co / COB;
  const int b  = blockIdx.z / coChunks;
  const int co0 = (blockIdx.z % coChunks) * COB;

  float acc[COB];
  #pragma unroll
  for (int i = 0; i < COB; ++i) acc[i] = bias[co0 + i];

  const float* ip = in + (size_t)b * Ci * HW;
  const float* wp = wt + (size_t)co0 * Ci * 9;

  for (int ci = 0; ci < Ci; ++ci) {
    float v[9];
    #pragma unroll
    for (int dy = 0; dy < 3; ++dy) {
      const int yy = y + dy - 1;
      #pragma unroll
      for (int dx = 0; dx < 3; ++dx) {
        const int xx = x + dx - 1;
        const bool ok = (yy >= 0) & (yy < 128) & (xx >= 0) & (xx < 128);
        v[dy*3+dx] = ok ? ip[(size_t)ci*HW + yy*128 + xx] : 0.f;
      }
    }
    #pragma unroll
    for (int co = 0; co < COB; ++co) {
      const float* w9 = wp + ((size_t)co * Ci + ci) * 9;   // thread-uniform -> s_load
      #pragma unroll
      for (int k = 0; k < 9; ++k) acc[co] = fmaf(v[k], w9[k], acc[co]);
    }
  }
  #pragma unroll
  for (int co = 0; co < COB; ++co)
    out[((size_t)(b * Co + co0 + co)) * HW + y*128 + x] = acc[co];
}

// ---------------- GroupNorm pass 1: per-(b,group) mean & rsqrt(var+eps) ----
__global__ __launch_bounds__(256) void gn_stats_k(
    const float* __restrict__ buf, float* __restrict__ mv, int C, int groups)
{
  const int bg = blockIdx.x;
  const int cpg = C / groups;
  const int b = bg / groups, g = bg % groups;
  const size_t base = ((size_t)b * C + (size_t)g * cpg) * HW;
  const int n = cpg * HW;
  const float4* p = (const float4*)(buf + base);
  const int n4 = n >> 2;

  float s = 0.f, ss = 0.f;
  for (int i = threadIdx.x; i < n4; i += 256) {
    float4 v = p[i];
    s  += v.x + v.y + v.z + v.w;
    ss += v.x*v.x + v.y*v.y + v.z*v.z + v.w*v.w;
  }
  __shared__ float r1[256], r2[256];
  r1[threadIdx.x] = s; r2[threadIdx.x] = ss;
  __syncthreads();
  for (int st = 128; st > 0; st >>= 1) {
    if (threadIdx.x < st) {
      r1[threadIdx.x] += r1[threadIdx.x + st];
      r2[threadIdx.x] += r2[threadIdx.x + st];
    }
    __syncthreads();
  }
  if (threadIdx.x == 0) {
    const float inv_n = 1.f / (float)n;
    const float mean = r1[0] * inv_n;
    const float var  = r2[0] * inv_n - mean * mean;
    mv[2*bg]   = mean;
    mv[2*bg+1] = rsqrtf(var + 1e-5f);
  }
}

// ---------------- GroupNorm pass 2: normalize + affine + ReLU (in place) ----
__global__ __launch_bounds__(256) void gn_apply_k(
    float* __restrict__ buf, const float* __restrict__ mv,
    const float* __restrict__ gw, const float* __restrict__ gb,
    int C, int groups)
{
  const int i = blockIdx.x * 256 + threadIdx.x;  // float4 index; grid sized exactly
  const int cpg = C / groups;
  const int bc = i >> 12;                        // 4096 float4 per 128x128 plane
  const int c = bc % C, b = bc / C;
  const int bg = b * groups + c / cpg;
  const float mean = mv[2*bg], inv = mv[2*bg+1];
  const float sc = inv * gw[c];
  const float sh = gb[c] - mean * sc;

  float4* p = (float4*)buf;
  float4 v = p[i];
  v.x = fmaxf(fmaf(v.x, sc, sh), 0.f);
  v.y = fmaxf(fmaf(v.y, sc, sh), 0.f);
  v.z = fmaxf(fmaf(v.z, sc, sh), 0.f);
  v.w = fmaxf(fmaf(v.w, sc, sh), 0.f);
  p[i] = v;
}

// ---------------- pooling: per-batch mask histogram (counts) ----------------
__global__ __launch_bounds__(256) void pool_counts_k(
    const int* __restrict__ masks, float* __restrict__ counts)
{
  __shared__ int hist[KIDS];
  const int b = blockIdx.x;
  if (threadIdx.x < KIDS) hist[threadIdx.x] = 0;
  __syncthreads();
  for (int p = threadIdx.x; p < HW; p += 256) {
    const int m = masks[b*HW + p];
    if (m > 0) atomicAdd(&hist[m-1], 1);
  }
  __syncthreads();
  if (threadIdx.x < KIDS) counts[b*KIDS + threadIdx.x] = (float)hist[threadIdx.x];
}

// ---------------- pooling: sums[b,k,c] via per-thread LDS bins --------------
// one block per (b,c): 256 blocks. No global atomics.
__global__ __launch_bounds__(256) void pool_sums_k(
    const float* __restrict__ h3, const int* __restrict__ masks,
    float* __restrict__ sums)
{
  const int bc = blockIdx.x;           // b*64 + c
  const int b = bc >> 6, c = bc & 63;
  __shared__ float acc[256][KIDS];     // 20 KiB
  #pragma unroll
  for (int k = 0; k < KIDS; ++k) acc[threadIdx.x][k] = 0.f;

  const float* hp = h3 + ((size_t)(b*64 + c)) * HW;
  const int*   mp = masks + b*HW;
  for (int p = threadIdx.x; p < HW; p += 256) {
    const int m = mp[p];
    if (m > 0) acc[threadIdx.x][m-1] += hp[p];
  }
  __syncthreads();
  if (threadIdx.x < KIDS) {
    float s = 0.f;
    for (int t = 0; t < 256; ++t) s += acc[t][threadIdx.x];
    sums[((size_t)b*KIDS + threadIdx.x)*64 + c] = s;
  }
}

// ---------------- heads: one wave per (b,k) ---------------------------------
__global__ __launch_bounds__(64) void heads_k(
    const float* __restrict__ sums, const float* __restrict__ counts,
    const float* __restrict__ wb, const float* __restrict__ bb,
    const float* __restrict__ wc, const float* __restrict__ bc,
    float* __restrict__ out)
{
  const int bk = blockIdx.x;        // 0..79
  const int c = threadIdx.x;        // 0..63
  const float pooled = sums[bk*64 + c] / (counts[bk] + 1e-6f);

  #pragma unroll
  for (int o = 0; o < 7; ++o) {
    float t = pooled * wb[o*64 + c];
    for (int off = 32; off > 0; off >>= 1) t += __shfl_down(t, off);
    if (c == 0) out[bk*7 + o] = t + bb[o];
  }
  float t = pooled * wc[c];
  for (int off = 32; off > 0; off >>= 1) t += __shfl_down(t, off);
  if (c == 0) out[BATCH*KIDS*7 + bk] = 1.f / (1.f + expf(-(t + bc[0])));
}

extern "C" void kernel_launch(void* const* d_in, const int* in_sizes, int n_in,
                              void* d_out, int out_size, void* d_ws, size_t ws_size,
                              hipStream_t stream)
{
  const float* x     = (const float*)d_in[0];
  const int*   masks = (const int*)  d_in[1];
  const float* w1 = (const float*)d_in[2];
  const float* b1 = (const float*)d_in[3];
  const float* g1w= (const float*)d_in[4];
  const float* g1b= (const float*)d_in[5];
  const float* w2 = (const float*)d_in[6];
  const float* b2 = (const float*)d_in[7];
  const float* g2w= (const float*)d_in[8];
  const float* g2b= (const float*)d_in[9];
  const float* w3 = (const float*)d_in[10];
  const float* b3 = (const float*)d_in[11];
  const float* g3w= (const float*)d_in[12];
  const float* g3b= (const float*)d_in[13];
  const float* wb = (const float*)d_in[14];
  const float* bb = (const float*)d_in[15];
  const float* wc = (const float*)d_in[16];
  const float* bc = (const float*)d_in[17];
  float* out = (float*)d_out;

  char* ws = (char*)d_ws;
  float* h1 = (float*)(ws);                        // 4*256*HW f32 = 64 MiB
  float* h2 = (float*)(ws + 67108864);             // 4*128*HW f32 = 32 MiB
  float* h3 = (float*)(ws);                        // alias h1 (free by conv3): 16 MiB
  float* mv     = (float*)(ws + 100663296);        // <=32 (mean, invstd) pairs
  float* sums   = (float*)(ws + 100663296 + 4096); // B*K*64 f32
  float* counts = (float*)(ws + 100663296 + 4096 + 32768); // B*K f32

  // layer 1: 512 -> 256, GN(8)
  conv3x3_k<512,8><<<dim3(8,8,BATCH*256/8), 256, 0, stream>>>(x, w1, b1, h1, 256);
  gn_stats_k<<<BATCH*8, 256, 0, stream>>>(h1, mv, 256, 8);
  gn_apply_k<<<16384, 256, 0, stream>>>(h1, mv, g1w, g1b, 256, 8);
  // layer 2: 256 -> 128, GN(4)
  conv3x3_k<256,8><<<dim3(8,8,BATCH*128/8), 256, 0, stream>>>(h1, w2, b2, h2, 128);
  gn_stats_k<<<BATCH*4, 256, 0, stream>>>(h2, mv, 128, 4);
  gn_apply_k<<<8192, 256, 0, stream>>>(h2, mv, g2w, g2b, 128, 4);
  // layer 3: 128 -> 64, GN(4)
  conv3x3_k<128,8><<<dim3(8,8,BATCH*64/8), 256, 0, stream>>>(h2, w3, b3, h3, 64);
  gn_stats_k<<<BATCH*4, 256, 0, stream>>>(h3, mv, 64, 4);
  gn_apply_k<<<4096, 256, 0, stream>>>(h3, mv, g3w, g3b, 64, 4);
  // pooling + heads
  pool_counts_k<<<BATCH, 256, 0, stream>>>(masks, counts);
  pool_sums_k<<<BATCH*64, 256, 0, stream>>>(h3, masks, sums);
  heads_k<<<BATCH*KIDS, 64, 0, stream>>>(sums, counts, wb, bb, wc, bc, out);
}

// Round 2
// 952.887 us; speedup vs baseline: 6.0321x; 6.0321x over previous
//
#include <hip/hip_runtime.h>
#include <hip/hip_bf16.h>
#include <math.h>

#define HW 16384      // 128*128
#define BATCH 4
#define KIDS 20

using short8 = __attribute__((ext_vector_type(8))) short;  // 8 bf16 = 16B
using f32x4  = __attribute__((ext_vector_type(4))) float;

__device__ __forceinline__ unsigned short bfbits(float f) {
  __hip_bfloat16 h = __float2bfloat16(f);
  return *(unsigned short*)&h;
}

// ---- x: fp32 NCHW [4][512][128][128] -> bf16 NHWC [4][16384][512] ----------
__global__ __launch_bounds__(256) void x_to_nhwc_k(const float* __restrict__ in,
                                                   __hip_bfloat16* __restrict__ out)
{
  __shared__ float tile[32][65];
  int t = blockIdx.x;
  const int pxt = t & 255; t >>= 8;     // 16384/64 = 256 px tiles
  const int ct  = t & 15;  t >>= 4;     // 512/32  = 16 ch tiles
  const int b   = t;
  const int tid = threadIdx.x;
  #pragma unroll
  for (int it = 0; it < 8; ++it) {
    int idx = tid + it*256;
    int px_l = idx & 63, c_l = idx >> 6;
    tile[c_l][px_l] = in[((size_t)(b*512 + ct*32 + c_l))*HW + pxt*64 + px_l];
  }
  __syncthreads();
  #pragma unroll
  for (int it = 0; it < 4; ++it) {
    int idx = tid + it*256;
    int c2 = idx & 15, px_l = idx >> 4;
    unsigned u = ((unsigned)bfbits(tile[c2*2+1][px_l]) << 16) | bfbits(tile[c2*2][px_l]);
    *(unsigned*)(out + ((size_t)(b*HW + pxt*64 + px_l))*512 + ct*32 + c2*2) = u;
  }
}

// ---- weights: fp32 [Co][Ci][3][3] -> bf16 [9][Co][Ci] ----------------------
template<int Co, int Ci>
__global__ __launch_bounds__(256) void pack_w_k(const float* __restrict__ w,
                                                __hip_bfloat16* __restrict__ out)
{
  const int i = blockIdx.x*256 + threadIdx.x;    // output-driven, grid exact
  const int ci = i & (Ci-1);
  const int r  = i >> __builtin_ctz(Ci);
  const int co = r & (Co-1);
  const int t  = r >> __builtin_ctz(Co);
  out[i] = __float2bfloat16(w[((size_t)co*Ci + ci)*9 + t]);
}

// ---- implicit-GEMM conv3x3 via MFMA ----------------------------------------
// block: 1 output row (128 px) x BM co. 4 waves. B staged in LDS (3 rows x
// 32ci, px-stride 40 bf16 -> only 2-way bank aliasing). A direct from L2.
template<int Ci, int Co, int BM, int MW, int NW>
__global__ __launch_bounds__(256) void conv_mfma_k(
    const __hip_bfloat16* __restrict__ xin,  // NHWC bf16 [4][16384][Ci]
    const __hip_bfloat16* __restrict__ wpk,  // [9][Co][Ci] bf16
    const float* __restrict__ bias,
    float* __restrict__ out)                 // NHWC fp32 [4][16384][Co]
{
  constexpr int WM = BM / MW;          // 64
  constexpr int WN = 128 / NW;         // 64 (2x2) or 32 (1x4)
  constexpr int MT = WM / 16;
  constexpr int NT = WN / 16;
  constexpr int LDP = 40;              // bf16 px-stride (20 dwords)
  __shared__ __align__(16) short bl[3*130*LDP];   // 31.2 KB

  const int row = blockIdx.x;          // b*128 + y
  const int b = row >> 7, y = row & 127;
  const int co0 = blockIdx.y * BM;
  const int tid = threadIdx.x;
  const int wave = tid >> 6, lane = tid & 63;
  const int wm = (MW == 1) ? 0 : (wave >> 1);
  const int wn = (MW == 1) ? wave : (wave & 1);
  const int lr = lane & 15, q = lane >> 4;

  // zero the x-pad slots (px = -1 and 128) once; never rewritten
  if (tid < 240) {
    int e = tid % 40, sp = tid / 40;
    int r = sp >> 1, s = (sp & 1) ? 129 : 0;
    bl[(r*130 + s)*LDP + e] = 0;
  }

  f32x4 acc[MT][NT] = {};
  const size_t in_base = (size_t)b * HW * Ci;

  for (int ci0 = 0; ci0 < Ci; ci0 += 32) {
    __syncthreads();
    // stage 3 rows x 128 px x 32 ci (4 x 16B chunks per px)
    #pragma unroll
    for (int it = 0; it < 6; ++it) {
      int idx = tid + it*256;
      int q16 = idx & 3, px = (idx >> 2) & 127, r = idx >> 9;
      int yy = y + r - 1;
      short8 v = {0,0,0,0,0,0,0,0};
      if ((unsigned)yy < 128u)
        v = *(const short8*)(xin + in_base + (size_t)(yy*128 + px)*Ci + ci0 + q16*8);
      *(short8*)(bl + (r*130 + px + 1)*LDP + q16*8) = v;
    }
    __syncthreads();
    #pragma unroll
    for (int t = 0; t < 9; ++t) {
      const int dy = t / 3, dx = t % 3;
      short8 af[MT], bf[NT];
      #pragma unroll
      for (int mt = 0; mt < MT; ++mt)
        af[mt] = *(const short8*)(wpk +
            ((size_t)(t*Co + co0 + wm*WM + mt*16 + lr))*Ci + ci0 + q*8);
      #pragma unroll
      for (int nt = 0; nt < NT; ++nt) {
        int px = wn*WN + nt*16 + lr;
        bf[nt] = *(const short8*)(bl + (dy*130 + px + dx)*LDP + q*8);
      }
      #pragma unroll
      for (int mt = 0; mt < MT; ++mt)
        #pragma unroll
        for (int nt = 0; nt < NT; ++nt)
          acc[mt][nt] = __builtin_amdgcn_mfma_f32_16x16x32_bf16(
              af[mt], bf[nt], acc[mt][nt], 0, 0, 0);
    }
  }

  #pragma unroll
  for (int mt = 0; mt < MT; ++mt) {
    #pragma unroll
    for (int nt = 0; nt < NT; ++nt) {
      int px = wn*WN + nt*16 + lr;
      int co = co0 + wm*WM + mt*16 + q*4;      // reg -> consecutive co
      const float4 bv = *(const float4*)(bias + co);
      f32x4 v = acc[mt][nt];
      v[0] += bv.x; v[1] += bv.y; v[2] += bv.z; v[3] += bv.w;
      *(f32x4*)(out + ((size_t)(b*HW + y*128 + px))*Co + co) = v;
    }
  }
}

// ---- GroupNorm stage 1: partial sums over px-chunks (NHWC) -----------------
template<int C, int CPG>
__global__ __launch_bounds__(256) void gn_partial_k(const float* __restrict__ buf,
                                                    float2* __restrict__ part)
{
  constexpr int G = C / CPG;
  constexpr int C4PG = CPG / 4;
  const int bg = blockIdx.x >> 3, blk = blockIdx.x & 7;  // 8 chunks per (b,g)
  const int b = bg / G, g = bg % G;
  const int tid = threadIdx.x;
  float s = 0.f, ss = 0.f;
  for (int i = tid; i < 2048*C4PG; i += 256) {
    int c4 = i & (C4PG-1);
    int px = (i >> __builtin_ctz(C4PG)) + blk*2048;
    float4 v = *(const float4*)(buf + ((size_t)(b*HW + px))*C + g*CPG + c4*4);
    s  += v.x+v.y+v.z+v.w;
    ss += v.x*v.x+v.y*v.y+v.z*v.z+v.w*v.w;
  }
  __shared__ float r1[256], r2[256];
  r1[tid]=s; r2[tid]=ss; __syncthreads();
  for (int st=128; st>0; st>>=1){
    if (tid<st){ r1[tid]+=r1[tid+st]; r2[tid]+=r2[tid+st]; }
    __syncthreads();
  }
  if (tid==0) part[blockIdx.x] = make_float2(r1[0], r2[0]);
}

__global__ void gn_final_k(const float2* __restrict__ part, float* __restrict__ mv,
                           int nbg, float inv_n)
{
  const int i = threadIdx.x;
  if (i < nbg) {
    float s=0.f, ss=0.f;
    for (int j=0;j<8;++j){ float2 p = part[i*8+j]; s+=p.x; ss+=p.y; }
    float mean = s*inv_n, var = ss*inv_n - mean*mean;
    mv[2*i] = mean; mv[2*i+1] = rsqrtf(var + 1e-5f);
  }
}

// ---- GroupNorm stage 2: normalize+affine+ReLU; emit bf16 (or fp32) NHWC ----
template<int C, int CPG, bool BF16OUT>
__global__ __launch_bounds__(256) void gn_apply_k(const float* __restrict__ in,
    const float* __restrict__ mv, const float* __restrict__ gw,
    const float* __restrict__ gb, void* __restrict__ outp)
{
  constexpr int C4 = C/4;
  constexpr int G = C/CPG;
  const int i = blockIdx.x*256 + threadIdx.x;       // float4 index, grid exact
  const int c4 = i & (C4-1);
  const int pxb = i >> __builtin_ctz(C4);
  const int b = pxb >> 14;
  const int c = c4*4;
  const int bg = b*G + c/CPG;
  const float mean = mv[2*bg], inv = mv[2*bg+1];
  float4 v = *((const float4*)in + i);
  const float4 w4 = *(const float4*)(gw + c);
  const float4 b4 = *(const float4*)(gb + c);
  float r0 = fmaxf((v.x-mean)*inv*w4.x + b4.x, 0.f);
  float r1 = fmaxf((v.y-mean)*inv*w4.y + b4.y, 0.f);
  float r2 = fmaxf((v.z-mean)*inv*w4.z + b4.z, 0.f);
  float r3 = fmaxf((v.w-mean)*inv*w4.w + b4.w, 0.f);
  if (BF16OUT) {
    uint2 o;
    o.x = ((unsigned)bfbits(r1) << 16) | bfbits(r0);
    o.y = ((unsigned)bfbits(r3) << 16) | bfbits(r2);
    *(uint2*)((__hip_bfloat16*)outp + (size_t)i*4) = o;
  } else {
    *((float4*)outp + i) = make_float4(r0,r1,r2,r3);
  }
}

// ---- pooling ---------------------------------------------------------------
__global__ __launch_bounds__(256) void pool_counts_k(
    const int* __restrict__ masks, float* __restrict__ counts)
{
  __shared__ int hist[KIDS];
  const int b = blockIdx.x;
  if (threadIdx.x < KIDS) hist[threadIdx.x] = 0;
  __syncthreads();
  for (int p = threadIdx.x; p < HW; p += 256) {
    const int m = masks[b*HW + p];
    if (m > 0) atomicAdd(&hist[m-1], 1);
  }
  __syncthreads();
  if (threadIdx.x < KIDS) counts[b*KIDS + threadIdx.x] = (float)hist[threadIdx.x];
}

__global__ __launch_bounds__(256) void zero_sums_k(float* __restrict__ sums)
{
  sums[blockIdx.x*256 + threadIdx.x] = 0.f;    // grid exact: 20*256 = 5120
}

// h3 fp32 NHWC [4][16384][64]; lane = channel, LDS acc + 1 global merge
__global__ __launch_bounds__(256) void pool_sums_k(const float* __restrict__ h3,
    const int* __restrict__ masks, float* __restrict__ sums)
{
  __shared__ float acc[KIDS*64];
  const int b = blockIdx.x >> 5, chunk = blockIdx.x & 31;   // 512 px per block
  const int tid = threadIdx.x;
  for (int j = tid; j < KIDS*64; j += 256) acc[j] = 0.f;
  __syncthreads();
  const int ch = tid & 63, pi = tid >> 6;
  const int p0 = chunk*512;
  for (int p = p0 + pi; p < p0 + 512; p += 4) {
    int m = masks[b*HW + p];
    if (m > 0) atomicAdd(&acc[(m-1)*64 + ch], h3[((size_t)(b*HW + p))*64 + ch]);
  }
  __syncthreads();
  for (int j = tid; j < KIDS*64; j += 256) atomicAdd(&sums[b*KIDS*64 + j], acc[j]);
}

// ---- heads: one wave per (b,k) ---------------------------------------------
__global__ __launch_bounds__(64) void heads_k(
    const float* __restrict__ sums, const float* __restrict__ counts,
    const float* __restrict__ wb, const float* __restrict__ bb,
    const float* __restrict__ wc, const float* __restrict__ bc,
    float* __restrict__ out)
{
  const int bk = blockIdx.x;
  const int c = threadIdx.x;
  const float pooled = sums[bk*64 + c] / (counts[bk] + 1e-6f);
  #pragma unroll
  for (int o = 0; o < 7; ++o) {
    float t = pooled * wb[o*64 + c];
    for (int off = 32; off > 0; off >>= 1) t += __shfl_down(t, off);
    if (c == 0) out[bk*7 + o] = t + bb[o];
  }
  float t = pooled * wc[c];
  for (int off = 32; off > 0; off >>= 1) t += __shfl_down(t, off);
  if (c == 0) out[BATCH*KIDS*7 + bk] = 1.f / (1.f + expf(-(t + bc[0])));
}

extern "C" void kernel_launch(void* const* d_in, const int* in_sizes, int n_in,
                              void* d_out, int out_size, void* d_ws, size_t ws_size,
                              hipStream_t stream)
{
  const float* x     = (const float*)d_in[0];
  const int*   masks = (const int*)  d_in[1];
  const float* w1 = (const float*)d_in[2];
  const float* b1 = (const float*)d_in[3];
  const float* g1w= (const float*)d_in[4];
  const float* g1b= (const float*)d_in[5];
  const float* w2 = (const float*)d_in[6];
  const float* b2 = (const float*)d_in[7];
  const float* g2w= (const float*)d_in[8];
  const float* g2b= (const float*)d_in[9];
  const float* w3 = (const float*)d_in[10];
  const float* b3 = (const float*)d_in[11];
  const float* g3w= (const float*)d_in[12];
  const float* g3b= (const float*)d_in[13];
  const float* wb = (const float*)d_in[14];
  const float* bb = (const float*)d_in[15];
  const float* wc = (const float*)d_in[16];
  const float* bc = (const float*)d_in[17];
  float* out = (float*)d_out;

  char* ws = (char*)d_ws;
  // region A [0,64MB): xb during conv1; then h1b(32) + h2b(16) + h3(16)
  __hip_bfloat16* xb  = (__hip_bfloat16*)ws;
  __hip_bfloat16* h1b = (__hip_bfloat16*)ws;
  __hip_bfloat16* h2b = (__hip_bfloat16*)(ws + (size_t)(32<<20));
  float*          h3  = (float*)         (ws + (size_t)(48<<20));
  // region B [64,128MB): c1(64); then c2(32)+c3(16)
  float* c1 = (float*)(ws + (size_t)(64<<20));
  float* c2 = c1;
  float* c3 = (float*)(ws + (size_t)(96<<20));
  // packed weights + small buffers at 128MB
  __hip_bfloat16* wp1 = (__hip_bfloat16*)(ws + (size_t)(128<<20));
  __hip_bfloat16* wp2 = wp1 + 9*256*512;
  __hip_bfloat16* wp3 = wp2 + 9*128*256;
  char* tail = (char*)(wp3 + 9*64*128);
  float2* part  = (float2*)tail;                  // up to 256 float2
  float* mv     = (float*)(tail + 4096);          // 64 floats
  float* sums   = (float*)(tail + 4096 + 512);    // 5120 floats
  float* counts = (float*)(tail + 4096 + 512 + 20480);

  x_to_nhwc_k<<<16384, 256, 0, stream>>>(x, xb);
  pack_w_k<256,512><<<4608, 256, 0, stream>>>(w1, wp1);
  pack_w_k<128,256><<<1152, 256, 0, stream>>>(w2, wp2);
  pack_w_k< 64,128><<< 288, 256, 0, stream>>>(w3, wp3);

  // layer 1: 512 -> 256, GN(8 groups, cpg 32)
  conv_mfma_k<512,256,128,2,2><<<dim3(512,2), 256, 0, stream>>>(xb, wp1, b1, c1);
  gn_partial_k<256,32><<<256, 256, 0, stream>>>(c1, part);
  gn_final_k<<<1, 64, 0, stream>>>(part, mv, 32, 1.f/(32.f*HW));
  gn_apply_k<256,32,true><<<16384, 256, 0, stream>>>(c1, mv, g1w, g1b, h1b);

  // layer 2: 256 -> 128, GN(4 groups, cpg 32)
  conv_mfma_k<256,128,128,2,2><<<dim3(512,1), 256, 0, stream>>>(h1b, wp2, b2, c2);
  gn_partial_k<128,32><<<128, 256, 0, stream>>>(c2, part);
  gn_final_k<<<1, 64, 0, stream>>>(part, mv, 16, 1.f/(32.f*HW));
  gn_apply_k<128,32,true><<<8192, 256, 0, stream>>>(c2, mv, g2w, g2b, h2b);

  // layer 3: 128 -> 64, GN(4 groups, cpg 16); fp32 out for pooling
  conv_mfma_k<128,64,64,1,4><<<dim3(512,1), 256, 0, stream>>>(h2b, wp3, b3, c3);
  gn_partial_k<64,16><<<128, 256, 0, stream>>>(c3, part);
  gn_final_k<<<1, 64, 0, stream>>>(part, mv, 16, 1.f/(16.f*HW));
  gn_apply_k<64,16,false><<<4096, 256, 0, stream>>>(c3, mv, g3w, g3b, h3);

  // pooling + heads
  pool_counts_k<<<BATCH, 256, 0, stream>>>(masks, counts);
  zero_sums_k<<<20, 256, 0, stream>>>(sums);
  pool_sums_k<<<BATCH*32, 256, 0, stream>>>(h3, masks, sums);
  heads_k<<<BATCH*KIDS, 64, 0, stream>>>(sums, counts, wb, bb, wc, bc, out);
}

// Round 3
// 879.096 us; speedup vs baseline: 6.5385x; 1.0839x over previous
//
#include <hip/hip_runtime.h>
#include <hip/hip_bf16.h>
#include <math.h>

#define HW 16384      // 128*128
#define BATCH 4
#define KIDS 20

using short8 = __attribute__((ext_vector_type(8))) short;  // 8 bf16 = 16B
using f32x4  = __attribute__((ext_vector_type(4))) float;

__device__ __forceinline__ unsigned short bfbits(float f) {
  __hip_bfloat16 h = __float2bfloat16(f);
  return *(unsigned short*)&h;
}

__global__ __launch_bounds__(256) void zero_k(float* __restrict__ p, int n) {
  int i = blockIdx.x*256 + threadIdx.x;
  if (i < n) p[i] = 0.f;
}

// ---- x: fp32 NCHW [4][512][128][128] -> bf16 NHWC [4][16384][512] ----------
__global__ __launch_bounds__(256) void x_to_nhwc_k(const float* __restrict__ in,
                                                   __hip_bfloat16* __restrict__ out)
{
  __shared__ float tile[32][65];
  int t = blockIdx.x;
  const int pxt = t & 255; t >>= 8;
  const int ct  = t & 15;  t >>= 4;
  const int b   = t;
  const int tid = threadIdx.x;
  #pragma unroll
  for (int it = 0; it < 8; ++it) {
    int idx = tid + it*256;
    int px_l = idx & 63, c_l = idx >> 6;
    tile[c_l][px_l] = in[((size_t)(b*512 + ct*32 + c_l))*HW + pxt*64 + px_l];
  }
  __syncthreads();
  #pragma unroll
  for (int it = 0; it < 4; ++it) {
    int idx = tid + it*256;
    int c2 = idx & 15, px_l = idx >> 4;
    unsigned u = ((unsigned)bfbits(tile[c2*2+1][px_l]) << 16) | bfbits(tile[c2*2][px_l]);
    *(unsigned*)(out + ((size_t)(b*HW + pxt*64 + px_l))*512 + ct*32 + c2*2) = u;
  }
}

// ---- weights: fp32 [Co][Ci][3][3] -> bf16 [9][Co][Ci] ----------------------
template<int Co, int Ci>
__global__ __launch_bounds__(256) void pack_w_k(const float* __restrict__ w,
                                                __hip_bfloat16* __restrict__ out)
{
  const int i = blockIdx.x*256 + threadIdx.x;
  const int ci = i & (Ci-1);
  const int r  = i >> __builtin_ctz(Ci);
  const int co = r & (Co-1);
  const int t  = r >> __builtin_ctz(Co);
  out[i] = __float2bfloat16(w[((size_t)co*Ci + ci)*9 + t]);
}

// ---- implicit-GEMM conv3x3 via MFMA + fused GN partial stats ---------------
// block: ROWS output rows x 64 co, 4 waves. wave = 1 row x (128/NW) px.
// LDS: (ROWS+2) rows x 130 px x 32 ci, px-stride 32 shorts (NO pad):
// addr pattern {16*px + 4*q} dwords tiles banks exactly -> conflict-free b128.
template<int Ci, int Co, int ROWS, int CPG>
__global__ __launch_bounds__(256, 2) void conv_mfma_k(
    const __hip_bfloat16* __restrict__ xin,  // NHWC bf16 [4][16384][Ci]
    const __hip_bfloat16* __restrict__ wpk,  // [9][Co][Ci] bf16
    const float* __restrict__ bias,
    float* __restrict__ out,                 // NHWC fp32 [4][16384][Co]
    float* __restrict__ partS, float* __restrict__ partSS)
{
  constexpr int NW = 4 / ROWS;         // waves along px
  constexpr int WN = 128 / NW;
  constexpr int NT = WN / 16;          // 8 (ROWS=4) or 4 (ROWS=2)
  constexpr int MT = 4;                // 64 co per block
  constexpr int SR = ROWS + 2;
  constexpr int RG = 128 / ROWS;
  constexpr int NG = 64 / CPG;         // groups covered per block
  __shared__ __align__(16) short bl[SR*130*32];

  const int b  = blockIdx.x / RG;
  const int r0 = (blockIdx.x % RG) * ROWS;
  const int co0 = blockIdx.y * 64;
  const int tid = threadIdx.x;
  const int wave = tid >> 6, lane = tid & 63;
  const int row_w = wave % ROWS;
  const int wn    = wave / ROWS;
  const int y = r0 + row_w;
  const int lr = lane & 15, q = lane >> 4;

  // zero the px-pad slots (px index 0 and 129) once
  if (tid < SR*2*4) {
    int q16 = tid & 3, sp = tid >> 2;
    int r = sp >> 1, side = sp & 1;
    short8 z = {0,0,0,0,0,0,0,0};
    *(short8*)(bl + (r*130 + (side ? 129 : 0))*32 + q16*8) = z;
  }

  f32x4 acc[MT][NT] = {};
  const size_t in_base = (size_t)b * HW * Ci;

  for (int ci0 = 0; ci0 < Ci; ci0 += 32) {
    __syncthreads();
    // stage SR rows x 128 px x 32 ci
    #pragma unroll
    for (int it = 0; it < 2*SR; ++it) {
      int idx = tid + it*256;
      int q16 = idx & 3, px = (idx >> 2) & 127, r = idx >> 9;
      int yy = r0 + r - 1;
      short8 v = {0,0,0,0,0,0,0,0};
      if ((unsigned)yy < 128u)
        v = *(const short8*)(xin + in_base + (size_t)(yy*128 + px)*Ci + ci0 + q16*8);
      *(short8*)(bl + (r*130 + px + 1)*32 + q16*8) = v;
    }
    __syncthreads();
    #pragma unroll
    for (int t = 0; t < 9; ++t) {
      const int dy = t / 3, dx = t % 3;
      short8 af[MT], bf[NT];
      #pragma unroll
      for (int mt = 0; mt < MT; ++mt)
        af[mt] = *(const short8*)(wpk +
            ((size_t)(t*Co + co0 + mt*16 + lr))*Ci + ci0 + q*8);
      #pragma unroll
      for (int nt = 0; nt < NT; ++nt) {
        int px = wn*WN + nt*16 + lr;
        bf[nt] = *(const short8*)(bl + ((row_w + dy)*130 + px + dx)*32 + q*8);
      }
      #pragma unroll
      for (int mt = 0; mt < MT; ++mt)
        #pragma unroll
        for (int nt = 0; nt < NT; ++nt)
          acc[mt][nt] = __builtin_amdgcn_mfma_f32_16x16x32_bf16(
              af[mt], bf[nt], acc[mt][nt], 0, 0, 0);
    }
  }

  // epilogue: +bias, store, and accumulate GN partial stats
  float sg[NG] = {}, ssg[NG] = {};
  #pragma unroll
  for (int mt = 0; mt < MT; ++mt) {
    const int g = (mt*16) / CPG;
    #pragma unroll
    for (int nt = 0; nt < NT; ++nt) {
      int px = wn*WN + nt*16 + lr;
      int co = co0 + mt*16 + q*4;
      const float4 bv = *(const float4*)(bias + co);
      f32x4 v = acc[mt][nt];
      v[0] += bv.x; v[1] += bv.y; v[2] += bv.z; v[3] += bv.w;
      sg[g]  += v[0] + v[1] + v[2] + v[3];
      ssg[g] += v[0]*v[0] + v[1]*v[1] + v[2]*v[2] + v[3]*v[3];
      *(f32x4*)(out + ((size_t)(b*HW + y*128 + px))*Co + co) = v;
    }
  }
  const int bgbase = b*(Co/CPG) + co0/CPG;
  #pragma unroll
  for (int g = 0; g < NG; ++g) {
    float s = sg[g], ss = ssg[g];
    #pragma unroll
    for (int off = 32; off; off >>= 1) {
      s  += __shfl_xor(s, off);
      ss += __shfl_xor(ss, off);
    }
    if (lane == 0) {
      atomicAdd(&partS[bgbase + g], s);
      atomicAdd(&partSS[bgbase + g], ss);
    }
  }
}

// ---- GN finalize: mean / rsqrt(var) from atomic partials -------------------
__global__ void gn_final_k(const float* __restrict__ partS,
                           const float* __restrict__ partSS,
                           float* __restrict__ mv, int nbg, float inv_n)
{
  const int i = threadIdx.x;
  if (i < nbg) {
    float s = partS[i], ss = partSS[i];
    float mean = s*inv_n, var = ss*inv_n - mean*mean;
    mv[2*i] = mean; mv[2*i+1] = rsqrtf(var + 1e-5f);
  }
}

// ---- GN apply: normalize+affine+ReLU; emit bf16 (or fp32) NHWC -------------
template<int C, int CPG, bool BF16OUT>
__global__ __launch_bounds__(256) void gn_apply_k(const float* __restrict__ in,
    const float* __restrict__ mv, const float* __restrict__ gw,
    const float* __restrict__ gb, void* __restrict__ outp)
{
  constexpr int C4 = C/4;
  constexpr int G = C/CPG;
  const int i = blockIdx.x*256 + threadIdx.x;
  const int c4 = i & (C4-1);
  const int pxb = i >> __builtin_ctz(C4);
  const int b = pxb >> 14;
  const int c = c4*4;
  const int bg = b*G + c/CPG;
  const float mean = mv[2*bg], inv = mv[2*bg+1];
  float4 v = *((const float4*)in + i);
  const float4 w4 = *(const float4*)(gw + c);
  const float4 b4 = *(const float4*)(gb + c);
  float r0 = fmaxf((v.x-mean)*inv*w4.x + b4.x, 0.f);
  float r1 = fmaxf((v.y-mean)*inv*w4.y + b4.y, 0.f);
  float r2 = fmaxf((v.z-mean)*inv*w4.z + b4.z, 0.f);
  float r3 = fmaxf((v.w-mean)*inv*w4.w + b4.w, 0.f);
  if (BF16OUT) {
    uint2 o;
    o.x = ((unsigned)bfbits(r1) << 16) | bfbits(r0);
    o.y = ((unsigned)bfbits(r3) << 16) | bfbits(r2);
    *(uint2*)((__hip_bfloat16*)outp + (size_t)i*4) = o;
  } else {
    *((float4*)outp + i) = make_float4(r0,r1,r2,r3);
  }
}

// ---- pooling ---------------------------------------------------------------
__global__ __launch_bounds__(256) void pool_counts_k(
    const int* __restrict__ masks, float* __restrict__ counts)
{
  __shared__ int hist[KIDS];
  const int b = blockIdx.x;
  if (threadIdx.x < KIDS) hist[threadIdx.x] = 0;
  __syncthreads();
  for (int p = threadIdx.x; p < HW; p += 256) {
    const int m = masks[b*HW + p];
    if (m > 0) atomicAdd(&hist[m-1], 1);
  }
  __syncthreads();
  if (threadIdx.x < KIDS) counts[b*KIDS + threadIdx.x] = (float)hist[threadIdx.x];
}

__global__ __launch_bounds__(256) void pool_sums_k(const float* __restrict__ h3,
    const int* __restrict__ masks, float* __restrict__ sums)
{
  __shared__ float acc[KIDS*64];
  const int b = blockIdx.x >> 5, chunk = blockIdx.x & 31;
  const int tid = threadIdx.x;
  for (int j = tid; j < KIDS*64; j += 256) acc[j] = 0.f;
  __syncthreads();
  const int ch = tid & 63, pi = tid >> 6;
  const int p0 = chunk*512;
  for (int p = p0 + pi; p < p0 + 512; p += 4) {
    int m = masks[b*HW + p];
    if (m > 0) atomicAdd(&acc[(m-1)*64 + ch], h3[((size_t)(b*HW + p))*64 + ch]);
  }
  __syncthreads();
  for (int j = tid; j < KIDS*64; j += 256) atomicAdd(&sums[b*KIDS*64 + j], acc[j]);
}

// ---- heads: one wave per (b,k) ---------------------------------------------
__global__ __launch_bounds__(64) void heads_k(
    const float* __restrict__ sums, const float* __restrict__ counts,
    const float* __restrict__ wb, const float* __restrict__ bb,
    const float* __restrict__ wc, const float* __restrict__ bc,
    float* __restrict__ out)
{
  const int bk = blockIdx.x;
  const int c = threadIdx.x;
  const float pooled = sums[bk*64 + c] / (counts[bk] + 1e-6f);
  #pragma unroll
  for (int o = 0; o < 7; ++o) {
    float t = pooled * wb[o*64 + c];
    for (int off = 32; off > 0; off >>= 1) t += __shfl_down(t, off);
    if (c == 0) out[bk*7 + o] = t + bb[o];
  }
  float t = pooled * wc[c];
  for (int off = 32; off > 0; off >>= 1) t += __shfl_down(t, off);
  if (c == 0) out[BATCH*KIDS*7 + bk] = 1.f / (1.f + expf(-(t + bc[0])));
}

extern "C" void kernel_launch(void* const* d_in, const int* in_sizes, int n_in,
                              void* d_out, int out_size, void* d_ws, size_t ws_size,
                              hipStream_t stream)
{
  const float* x     = (const float*)d_in[0];
  const int*   masks = (const int*)  d_in[1];
  const float* w1 = (const float*)d_in[2];
  const float* b1 = (const float*)d_in[3];
  const float* g1w= (const float*)d_in[4];
  const float* g1b= (const float*)d_in[5];
  const float* w2 = (const float*)d_in[6];
  const float* b2 = (const float*)d_in[7];
  const float* g2w= (const float*)d_in[8];
  const float* g2b= (const float*)d_in[9];
  const float* w3 = (const float*)d_in[10];
  const float* b3 = (const float*)d_in[11];
  const float* g3w= (const float*)d_in[12];
  const float* g3b= (const float*)d_in[13];
  const float* wb = (const float*)d_in[14];
  const float* bb = (const float*)d_in[15];
  const float* wc = (const float*)d_in[16];
  const float* bc = (const float*)d_in[17];
  float* out = (float*)d_out;

  char* ws = (char*)d_ws;
  // region A [0,64MB): xb during conv1; then h1b(32) + h2b(16) + h3(16)
  __hip_bfloat16* xb  = (__hip_bfloat16*)ws;
  __hip_bfloat16* h1b = (__hip_bfloat16*)ws;
  __hip_bfloat16* h2b = (__hip_bfloat16*)(ws + (size_t)(32<<20));
  float*          h3  = (float*)         (ws + (size_t)(48<<20));
  // region B [64,128MB): c1(64); then c2(32)+c3(16)
  float* c1 = (float*)(ws + (size_t)(64<<20));
  float* c2 = c1;
  float* c3 = (float*)(ws + (size_t)(96<<20));
  // packed weights + small buffers at 128MB
  __hip_bfloat16* wp1 = (__hip_bfloat16*)(ws + (size_t)(128<<20));
  __hip_bfloat16* wp2 = wp1 + 9*256*512;
  __hip_bfloat16* wp3 = wp2 + 9*128*256;
  char* tail = (char*)(wp3 + 9*64*128);
  float* mv     = (float*)tail;                 // 64 floats
  float* partS  = mv + 64;                      // 64 (layer offs 0/32/48)
  float* partSS = partS + 64;                   // 64
  float* sums   = partSS + 64;                  // 5120
  float* counts = sums + 5120;                  // 80

  // zero atomic accumulators (partS, partSS, sums are contiguous: 5248 floats)
  zero_k<<<21, 256, 0, stream>>>(partS, 64 + 64 + 5120);

  x_to_nhwc_k<<<16384, 256, 0, stream>>>(x, xb);
  pack_w_k<256,512><<<4608, 256, 0, stream>>>(w1, wp1);
  pack_w_k<128,256><<<1152, 256, 0, stream>>>(w2, wp2);
  pack_w_k< 64,128><<< 288, 256, 0, stream>>>(w3, wp3);

  // layer 1: 512 -> 256, GN(8 groups, cpg 32)
  conv_mfma_k<512,256,4,32><<<dim3(128,4), 256, 0, stream>>>(
      xb, wp1, b1, c1, partS, partSS);
  gn_final_k<<<1, 64, 0, stream>>>(partS, partSS, mv, 32, 1.f/(32.f*HW));
  gn_apply_k<256,32,true><<<16384, 256, 0, stream>>>(c1, mv, g1w, g1b, h1b);

  // layer 2: 256 -> 128, GN(4 groups, cpg 32)
  conv_mfma_k<256,128,2,32><<<dim3(256,2), 256, 0, stream>>>(
      h1b, wp2, b2, c2, partS + 32, partSS + 32);
  gn_final_k<<<1, 64, 0, stream>>>(partS + 32, partSS + 32, mv, 16, 1.f/(32.f*HW));
  gn_apply_k<128,32,true><<<8192, 256, 0, stream>>>(c2, mv, g2w, g2b, h2b);

  // layer 3: 128 -> 64, GN(4 groups, cpg 16); fp32 out for pooling
  conv_mfma_k<128,64,2,16><<<dim3(256,1), 256, 0, stream>>>(
      h2b, wp3, b3, c3, partS + 48, partSS + 48);
  gn_final_k<<<1, 64, 0, stream>>>(partS + 48, partSS + 48, mv, 16, 1.f/(16.f*HW));
  gn_apply_k<64,16,false><<<4096, 256, 0, stream>>>(c3, mv, g3w, g3b, h3);

  // pooling + heads
  pool_counts_k<<<BATCH, 256, 0, stream>>>(masks, counts);
  pool_sums_k<<<BATCH*32, 256, 0, stream>>>(h3, masks, sums);
  heads_k<<<BATCH*KIDS, 64, 0, stream>>>(sums, counts, wb, bb, wc, bc, out);
}